// Round 1
// baseline (876.609 us; speedup 1.0000x reference)
//
#include <hip/hip_runtime.h>
#include <math.h>

typedef __bf16 bf16;
typedef bf16 bf16x8 __attribute__((ext_vector_type(8)));
typedef float floatx4 __attribute__((ext_vector_type(4)));

static constexpr int Bc = 4, Sq = 2048, Dm = 1024, Hh = 16, HDim = 64;
static constexpr int Mrows = Bc * Sq; // 8192

// ---------------------------------------------------------------------------
// Kernel 1: QKV projection.  x(8192x1024) @ W(1024x1024) -> bf16 [B,H,S,HD]
// blockIdx.z selects Wq/Wk/Wv.  Block tile 64x128, BK=32, 4 waves (2x2),
// each wave 32x64 = 2x4 MFMA 16x16x32 tiles.
// ---------------------------------------------------------------------------
__global__ __launch_bounds__(256)
void qkv_gemm(const float* __restrict__ x,
              const float* __restrict__ Wq,
              const float* __restrict__ Wk,
              const float* __restrict__ Wv,
              bf16* __restrict__ Qb, bf16* __restrict__ Kb, bf16* __restrict__ Vb)
{
    const int zz = blockIdx.z;
    const float* W = (zz == 0) ? Wq : ((zz == 1) ? Wk : Wv);
    bf16* dst = (zz == 0) ? Qb : ((zz == 1) ? Kb : Vb);

    __shared__ __align__(16) bf16 As[64][40];    // [m][k], stride 40 (80B, 16B-aligned rows)
    __shared__ __align__(16) bf16 Wt[128][40];   // [n][k] (W transposed)

    const int tid  = threadIdx.x;
    const int wave = tid >> 6;
    const int lane = tid & 63;
    const int quad = lane >> 4;
    const int l16  = lane & 15;

    const int bm = blockIdx.y * 64;
    const int bn = blockIdx.x * 128;
    const int wm = (wave >> 1) * 32;
    const int wn = (wave & 1) * 64;

    floatx4 acc[2][4];
#pragma unroll
    for (int i = 0; i < 2; i++)
#pragma unroll
        for (int j = 0; j < 4; j++) acc[i][j] = (floatx4){0.f, 0.f, 0.f, 0.f};

    const int am  = tid >> 2;          // 0..63 (A row)
    const int ak  = (tid & 3) * 8;     // 0/8/16/24 (A k-chunk)
    const int wk  = tid >> 5;          // 0..7 (W k base)
    const int wn4 = (tid & 31) * 4;    // 0..124 (W n chunk)

    for (int k0 = 0; k0 < 1024; k0 += 32) {
        __syncthreads();
        // stage A: x[bm+am][k0+ak .. +7], fp32 -> bf16
        {
            const float* src = x + (size_t)(bm + am) * 1024 + k0 + ak;
            float4 f0 = *(const float4*)(src);
            float4 f1 = *(const float4*)(src + 4);
            bf16x8 v;
            v[0] = (bf16)f0.x; v[1] = (bf16)f0.y; v[2] = (bf16)f0.z; v[3] = (bf16)f0.w;
            v[4] = (bf16)f1.x; v[5] = (bf16)f1.y; v[6] = (bf16)f1.z; v[7] = (bf16)f1.w;
            *(bf16x8*)&As[am][ak] = v;
        }
        // stage W transposed: read W[k][n] coalesced, write Wt[n][k]
#pragma unroll
        for (int p = 0; p < 4; p++) {
            int k = wk + p * 8;
            float4 f = *(const float4*)(W + (size_t)(k0 + k) * 1024 + bn + wn4);
            Wt[wn4 + 0][k] = (bf16)f.x;
            Wt[wn4 + 1][k] = (bf16)f.y;
            Wt[wn4 + 2][k] = (bf16)f.z;
            Wt[wn4 + 3][k] = (bf16)f.w;
        }
        __syncthreads();

        bf16x8 a[2], b[4];
#pragma unroll
        for (int tm = 0; tm < 2; tm++)
            a[tm] = *(const bf16x8*)&As[wm + tm * 16 + l16][quad * 8];
#pragma unroll
        for (int tn = 0; tn < 4; tn++)
            b[tn] = *(const bf16x8*)&Wt[wn + tn * 16 + l16][quad * 8];
#pragma unroll
        for (int tm = 0; tm < 2; tm++)
#pragma unroll
            for (int tn = 0; tn < 4; tn++)
                acc[tm][tn] = __builtin_amdgcn_mfma_f32_16x16x32_bf16(a[tm], b[tn], acc[tm][tn], 0, 0, 0);
    }

    // epilogue: scatter to [B,H,S,HD] bf16.  row=quad*4+r, col=l16 (verified C/D map)
#pragma unroll
    for (int tm = 0; tm < 2; tm++) {
#pragma unroll
        for (int tn = 0; tn < 4; tn++) {
#pragma unroll
            for (int r = 0; r < 4; r++) {
                int m = bm + wm + tm * 16 + quad * 4 + r;
                int n = bn + wn + tn * 16 + l16;
                int bb = m >> 11, s = m & 2047;
                int h = n >> 6, d = n & 63;
                dst[(((size_t)(bb * Hh + h)) * Sq + s) * HDim + d] = (bf16)acc[tm][tn][r];
            }
        }
    }
}

// ---------------------------------------------------------------------------
// Kernel 2: flash-style causal attention.
// grid = (32 q-tiles, 64 bh).  Block 256 = 4 waves, each wave 16 query rows.
// K-tile of 64 keys per iteration, kt = 0..qt (causal).
// ---------------------------------------------------------------------------
__global__ __launch_bounds__(256)
void attn(const bf16* __restrict__ Qb, const bf16* __restrict__ Kb,
          const bf16* __restrict__ Vb, bf16* __restrict__ ctx)
{
    const int qt = blockIdx.x;       // 0..31
    const int bh = blockIdx.y;       // 0..63
    const int bb = bh >> 4, h = bh & 15;

    __shared__ __align__(16) bf16 Kl[64][72];      // [key][hd]
    __shared__ __align__(16) bf16 Vt[64][72];      // [hd][key]  (transposed)
    __shared__ __align__(16) bf16 Pl[4][16][72];   // per-wave P round-trip

    const int tid  = threadIdx.x;
    const int wave = tid >> 6;
    const int lane = tid & 63;
    const int quad = lane >> 4;
    const int l16  = lane & 15;

    const int q0 = qt * 64 + wave * 16;   // wave's first query row

    // Q fragments (A-operand layout): A[m=l16][k=quad*8+j], k-steps 0,32
    const bf16* Qrow = Qb + ((size_t)bh * Sq + q0 + l16) * HDim;
    bf16x8 aq[2];
    aq[0] = *(const bf16x8*)(Qrow + quad * 8);
    aq[1] = *(const bf16x8*)(Qrow + 32 + quad * 8);

    floatx4 acc_o[4];
#pragma unroll
    for (int i = 0; i < 4; i++) acc_o[i] = (floatx4){0.f, 0.f, 0.f, 0.f};
    float m_old[4], l_sum[4];
#pragma unroll
    for (int r = 0; r < 4; r++) { m_old[r] = -1e30f; l_sum[r] = 0.f; }

    const int sr = tid >> 2;          // staging row 0..63
    const int sc = (tid & 3) * 16;    // staging col base

    for (int kt = 0; kt <= qt; kt++) {
        __syncthreads();
        // stage K tile + transposed V tile
        {
            const bf16* ks = Kb + ((size_t)bh * Sq + kt * 64 + sr) * HDim + sc;
            *(bf16x8*)&Kl[sr][sc]     = *(const bf16x8*)ks;
            *(bf16x8*)&Kl[sr][sc + 8] = *(const bf16x8*)(ks + 8);
            const bf16* vs = Vb + ((size_t)bh * Sq + kt * 64 + sr) * HDim + sc;
            bf16x8 w0 = *(const bf16x8*)vs;
            bf16x8 w1 = *(const bf16x8*)(vs + 8);
#pragma unroll
            for (int i = 0; i < 8; i++) {
                Vt[sc + i][sr]     = w0[i];
                Vt[sc + 8 + i][sr] = w1[i];
            }
        }
        __syncthreads();

        // S = Q @ K^T   (B-frag: B[k][n]=K[n][k] -> contiguous K rows)
        floatx4 s[4];
#pragma unroll
        for (int tn = 0; tn < 4; tn++) {
            bf16x8 bk0 = *(const bf16x8*)&Kl[tn * 16 + l16][quad * 8];
            bf16x8 bk1 = *(const bf16x8*)&Kl[tn * 16 + l16][32 + quad * 8];
            floatx4 z = (floatx4){0.f, 0.f, 0.f, 0.f};
            z = __builtin_amdgcn_mfma_f32_16x16x32_bf16(aq[0], bk0, z, 0, 0, 0);
            z = __builtin_amdgcn_mfma_f32_16x16x32_bf16(aq[1], bk1, z, 0, 0, 0);
            s[tn] = z;
        }

        // causal mask on the diagonal tile, then scale
        if (kt == qt) {
#pragma unroll
            for (int tn = 0; tn < 4; tn++)
#pragma unroll
                for (int r = 0; r < 4; r++) {
                    int key  = kt * 64 + tn * 16 + l16;
                    int qrow = q0 + quad * 4 + r;
                    if (key > qrow) s[tn][r] = -1e30f;
                }
        }
        const float scale = 0.125f;   // 1/sqrt(64)
#pragma unroll
        for (int tn = 0; tn < 4; tn++)
#pragma unroll
            for (int r = 0; r < 4; r++) s[tn][r] *= scale;

        // online softmax: row stats live in quad-lanes (row = quad*4+r)
        float p[4][4], alpha[4];
#pragma unroll
        for (int r = 0; r < 4; r++) {
            float mx = fmaxf(fmaxf(s[0][r], s[1][r]), fmaxf(s[2][r], s[3][r]));
#pragma unroll
            for (int off = 8; off >= 1; off >>= 1)
                mx = fmaxf(mx, __shfl_xor(mx, off, 64));
            float mn = fmaxf(m_old[r], mx);
            alpha[r] = __expf(m_old[r] - mn);
            m_old[r] = mn;
            float rs = 0.f;
#pragma unroll
            for (int tn = 0; tn < 4; tn++) {
                float e = __expf(s[tn][r] - mn);
                p[tn][r] = e;
                rs += e;
            }
#pragma unroll
            for (int off = 8; off >= 1; off >>= 1)
                rs += __shfl_xor(rs, off, 64);
            l_sum[r] = l_sum[r] * alpha[r] + rs;
        }

        // write P (C-layout) to LDS; rescale O accumulator
#pragma unroll
        for (int tn = 0; tn < 4; tn++) {
#pragma unroll
            for (int r = 0; r < 4; r++) {
                Pl[wave][quad * 4 + r][tn * 16 + l16] = (bf16)p[tn][r];
                acc_o[tn][r] *= alpha[r];
            }
        }
        __syncthreads();

        // PV: A-frag from Pl (A-layout), B-frag from Vt (contiguous rows)
        bf16x8 ap0 = *(const bf16x8*)&Pl[wave][l16][quad * 8];
        bf16x8 ap1 = *(const bf16x8*)&Pl[wave][l16][32 + quad * 8];
#pragma unroll
        for (int tn = 0; tn < 4; tn++) {
            bf16x8 bv0 = *(const bf16x8*)&Vt[tn * 16 + l16][quad * 8];
            bf16x8 bv1 = *(const bf16x8*)&Vt[tn * 16 + l16][32 + quad * 8];
            acc_o[tn] = __builtin_amdgcn_mfma_f32_16x16x32_bf16(ap0, bv0, acc_o[tn], 0, 0, 0);
            acc_o[tn] = __builtin_amdgcn_mfma_f32_16x16x32_bf16(ap1, bv1, acc_o[tn], 0, 0, 0);
        }
    }

    // epilogue: ctx[b][s][h*64+d] bf16
#pragma unroll
    for (int tn = 0; tn < 4; tn++) {
#pragma unroll
        for (int r = 0; r < 4; r++) {
            int qrow = q0 + quad * 4 + r;
            int dcol = tn * 16 + l16;
            float o = acc_o[tn][r] / l_sum[r];
            ctx[((size_t)(bb * Sq + qrow)) * Dm + h * HDim + dcol] = (bf16)o;
        }
    }
}

// ---------------------------------------------------------------------------
// Kernel 3: output projection.  ctx(8192x1024 bf16) @ Wo + bo -> fp32 out
// ---------------------------------------------------------------------------
__global__ __launch_bounds__(256)
void out_gemm(const bf16* __restrict__ Ab, const float* __restrict__ Wo,
              const float* __restrict__ bo, float* __restrict__ out)
{
    __shared__ __align__(16) bf16 As[64][40];
    __shared__ __align__(16) bf16 Wt[128][40];

    const int tid  = threadIdx.x;
    const int wave = tid >> 6;
    const int lane = tid & 63;
    const int quad = lane >> 4;
    const int l16  = lane & 15;

    const int bm = blockIdx.y * 64;
    const int bn = blockIdx.x * 128;
    const int wm = (wave >> 1) * 32;
    const int wn = (wave & 1) * 64;

    floatx4 acc[2][4];
#pragma unroll
    for (int i = 0; i < 2; i++)
#pragma unroll
        for (int j = 0; j < 4; j++) acc[i][j] = (floatx4){0.f, 0.f, 0.f, 0.f};

    const int am  = tid >> 2;
    const int ak  = (tid & 3) * 8;
    const int wk  = tid >> 5;
    const int wn4 = (tid & 31) * 4;

    for (int k0 = 0; k0 < 1024; k0 += 32) {
        __syncthreads();
        {
            const bf16* src = Ab + (size_t)(bm + am) * 1024 + k0 + ak;
            *(bf16x8*)&As[am][ak] = *(const bf16x8*)src;
        }
#pragma unroll
        for (int p = 0; p < 4; p++) {
            int k = wk + p * 8;
            float4 f = *(const float4*)(Wo + (size_t)(k0 + k) * 1024 + bn + wn4);
            Wt[wn4 + 0][k] = (bf16)f.x;
            Wt[wn4 + 1][k] = (bf16)f.y;
            Wt[wn4 + 2][k] = (bf16)f.z;
            Wt[wn4 + 3][k] = (bf16)f.w;
        }
        __syncthreads();

        bf16x8 a[2], b[4];
#pragma unroll
        for (int tm = 0; tm < 2; tm++)
            a[tm] = *(const bf16x8*)&As[wm + tm * 16 + l16][quad * 8];
#pragma unroll
        for (int tn = 0; tn < 4; tn++)
            b[tn] = *(const bf16x8*)&Wt[wn + tn * 16 + l16][quad * 8];
#pragma unroll
        for (int tm = 0; tm < 2; tm++)
#pragma unroll
            for (int tn = 0; tn < 4; tn++)
                acc[tm][tn] = __builtin_amdgcn_mfma_f32_16x16x32_bf16(a[tm], b[tn], acc[tm][tn], 0, 0, 0);
    }

#pragma unroll
    for (int tm = 0; tm < 2; tm++) {
#pragma unroll
        for (int tn = 0; tn < 4; tn++) {
#pragma unroll
            for (int r = 0; r < 4; r++) {
                int m = bm + wm + tm * 16 + quad * 4 + r;
                int n = bn + wn + tn * 16 + l16;
                out[(size_t)m * 1024 + n] = acc[tm][tn][r] + bo[n];
            }
        }
    }
}

// ---------------------------------------------------------------------------
extern "C" void kernel_launch(void* const* d_in, const int* in_sizes, int n_in,
                              void* d_out, int out_size, void* d_ws, size_t ws_size,
                              hipStream_t stream)
{
    const float* x  = (const float*)d_in[0];
    const float* Wq = (const float*)d_in[1];
    const float* Wk = (const float*)d_in[2];
    const float* Wv = (const float*)d_in[3];
    const float* Wo = (const float*)d_in[4];
    const float* bo = (const float*)d_in[5];
    float* out = (float*)d_out;

    const size_t SZ = (size_t)Mrows * Dm;   // 8,388,608 elements
    bf16* Qb = (bf16*)d_ws;                 // 16 MB each, bf16
    bf16* Kb = Qb + SZ;
    bf16* Vb = Kb + SZ;
    bf16* Cx = Vb + SZ;                     // ctx [B,S,D] bf16

    qkv_gemm<<<dim3(8, 128, 3), 256, 0, stream>>>(x, Wq, Wk, Wv, Qb, Kb, Vb);
    attn<<<dim3(32, 64), 256, 0, stream>>>(Qb, Kb, Vb, Cx);
    out_gemm<<<dim3(8, 128), 256, 0, stream>>>(Cx, Wo, bo, out);
}

// Round 2
// 421.067 us; speedup vs baseline: 2.0819x; 2.0819x over previous
//
#include <hip/hip_runtime.h>
#include <math.h>
#include <stdint.h>

typedef __bf16 bf16;
typedef bf16 bf16x8 __attribute__((ext_vector_type(8)));
typedef float floatx4 __attribute__((ext_vector_type(4)));

static constexpr int Sq = 2048, Dm = 1024, Hh = 16, HDim = 64;

#define GAS __attribute__((address_space(1)))
#define LAS __attribute__((address_space(3)))

// async global->LDS DMA, 16 B per lane.  lds ptr must be wave-uniform;
// HW writes lane i's 16 B at ldsbase + i*16.
__device__ __forceinline__ void dma16(const void* g, void* l) {
    __builtin_amdgcn_global_load_lds((const GAS void*)g, (LAS void*)l, 16, 0, 0);
}

__device__ __forceinline__ uint32_t pk_bf16(float a, float b) {
    unsigned short lo = __builtin_bit_cast(unsigned short, (bf16)a);
    unsigned short hi = __builtin_bit_cast(unsigned short, (bf16)b);
    return (uint32_t)lo | ((uint32_t)hi << 16);
}

// ---------------------------------------------------------------------------
// Kernel 0: weight prep.  W fp32 [k][n] -> Wt bf16 [n][k], 4 matrices.
// 64x64 tiles; dword = bf16 pair (k, k+1) so all LDS traffic is b32.
// Write banks: (8*(t&7)+j + (t>>3)) % 32 -> 2 lanes/bank (free).
// ---------------------------------------------------------------------------
__global__ __launch_bounds__(256)
void prep_weights(const float* __restrict__ Wq, const float* __restrict__ Wk,
                  const float* __restrict__ Wv, const float* __restrict__ Wo,
                  bf16* __restrict__ Wt)
{
    const int w = blockIdx.z;
    const float* W = (w == 0) ? Wq : (w == 1) ? Wk : (w == 2) ? Wv : Wo;
    bf16* dst = Wt + (size_t)w * 1024 * 1024;
    const int k0 = blockIdx.x * 64, n0 = blockIdx.y * 64;
    __shared__ uint32_t Tl[64][33];   // [col][kpair], pad 33 (33 % 32 == 1)
    const int t = threadIdx.x;
    {
        const int c8 = (t & 7) * 8;   // col group
        const int kp = t >> 3;        // k-pair 0..31
        const float* r0 = W + (size_t)(k0 + 2 * kp) * 1024 + n0 + c8;
        const float* r1 = r0 + 1024;
        float4 a0 = *(const float4*)r0, a1 = *(const float4*)(r0 + 4);
        float4 b0 = *(const float4*)r1, b1 = *(const float4*)(r1 + 4);
        float ra[8] = {a0.x, a0.y, a0.z, a0.w, a1.x, a1.y, a1.z, a1.w};
        float rb[8] = {b0.x, b0.y, b0.z, b0.w, b1.x, b1.y, b1.z, b1.w};
#pragma unroll
        for (int j = 0; j < 8; j++)
            Tl[c8 + j][kp] = pk_bf16(ra[j], rb[j]);
    }
    __syncthreads();
    {
        const int c = t >> 2, dq = (t & 3) * 8;
        uint32_t d[8];
#pragma unroll
        for (int i = 0; i < 8; i++) d[i] = Tl[c][dq + i];
        uint32_t* o = (uint32_t*)(dst + (size_t)(n0 + c) * 1024 + k0 + dq * 2);
        *(uint4*)o       = make_uint4(d[0], d[1], d[2], d[3]);
        *(uint4*)(o + 4) = make_uint4(d[4], d[5], d[6], d[7]);
    }
}

// ---------------------------------------------------------------------------
// Kernel 1: QKV projection.  x(8192x1024 fp32) @ W -> Q,K [bh][s][d] bf16,
// V written TRANSPOSED [bh][d][s].  128x128 tile, BK=64, 4 waves each 64x64.
// A: fp32->bf16 via padded-72 LDS (conflict-free write/read patterns).
// B: global_load_lds dwordx4 into [128][64] with 16B-block swizzle ^(n&7).
// ---------------------------------------------------------------------------
__global__ __launch_bounds__(256, 2)
void qkv_gemm(const float* __restrict__ x, const bf16* __restrict__ Wt,
              bf16* __restrict__ Qb, bf16* __restrict__ Kb, bf16* __restrict__ VT)
{
    const int zz = blockIdx.z;
    const bf16* Wsel = Wt + (size_t)zz * 1024 * 1024;

    __shared__ __align__(16) unsigned char smem[34816];
    bf16 (*As)[72] = (bf16(*)[72])smem;            // 128x72x2 = 18432 B
    bf16 (*Bs)[64] = (bf16(*)[64])(smem + 18432);  // 128x64x2 = 16384 B

    const int tid  = threadIdx.x;
    const int wave = tid >> 6, lane = tid & 63, quad = lane >> 4, l16 = lane & 15;
    const int bm = blockIdx.y * 128, bn = blockIdx.x * 128;
    const int wm = (wave >> 1) * 64, wn = (wave & 1) * 64;

    floatx4 acc[4][4];
#pragma unroll
    for (int i = 0; i < 4; i++)
#pragma unroll
        for (int j = 0; j < 4; j++) acc[i][j] = (floatx4){0.f, 0.f, 0.f, 0.f};

    for (int k0 = 0; k0 < 1024; k0 += 64) {
        __syncthreads();
        // B tile via async DMA (4 x 1KB per wave)
#pragma unroll
        for (int i = 0; i < 4; i++) {
            const int row = wave * 32 + i * 8 + (lane >> 3);
            const int lb  = (lane & 7) ^ (row & 7);     // logical 16B block
            const bf16* g = Wsel + (size_t)(bn + row) * 1024 + k0 + lb * 8;
            dma16((const void*)g, (void*)&Bs[wave * 32 + i * 8][0]);
        }
        // A tile: fp32 load -> bf16 -> LDS (stride 72)
#pragma unroll
        for (int it = 0; it < 2; it++) {
            const int r  = (tid >> 2) + it * 64;
            const int cq = (tid & 3) * 16;
            const float* src = x + (size_t)(bm + r) * 1024 + k0 + cq;
            float4 f0 = *(const float4*)src,       f1 = *(const float4*)(src + 4);
            float4 f2 = *(const float4*)(src + 8), f3 = *(const float4*)(src + 12);
            bf16x8 v0, v1;
            v0[0]=(bf16)f0.x; v0[1]=(bf16)f0.y; v0[2]=(bf16)f0.z; v0[3]=(bf16)f0.w;
            v0[4]=(bf16)f1.x; v0[5]=(bf16)f1.y; v0[6]=(bf16)f1.z; v0[7]=(bf16)f1.w;
            v1[0]=(bf16)f2.x; v1[1]=(bf16)f2.y; v1[2]=(bf16)f2.z; v1[3]=(bf16)f2.w;
            v1[4]=(bf16)f3.x; v1[5]=(bf16)f3.y; v1[6]=(bf16)f3.z; v1[7]=(bf16)f3.w;
            *(bf16x8*)&As[r][cq]     = v0;
            *(bf16x8*)&As[r][cq + 8] = v1;
        }
        __syncthreads();

#pragma unroll
        for (int kk = 0; kk < 2; kk++) {
            bf16x8 a[4], b[4];
#pragma unroll
            for (int tm = 0; tm < 4; tm++)
                a[tm] = *(const bf16x8*)&As[wm + tm * 16 + l16][kk * 32 + quad * 8];
#pragma unroll
            for (int tn = 0; tn < 4; tn++) {
                const int n = wn + tn * 16 + l16;
                const int phys = (kk * 4 + quad) ^ (n & 7);
                b[tn] = *(const bf16x8*)&Bs[n][phys * 8];
            }
#pragma unroll
            for (int tm = 0; tm < 4; tm++)
#pragma unroll
                for (int tn = 0; tn < 4; tn++)
                    acc[tm][tn] = __builtin_amdgcn_mfma_f32_16x16x32_bf16(a[tm], b[tn], acc[tm][tn], 0, 0, 0);
        }
    }

    if (zz < 2) {
        bf16* dst = (zz == 0) ? Qb : Kb;
#pragma unroll
        for (int tm = 0; tm < 4; tm++)
#pragma unroll
            for (int tn = 0; tn < 4; tn++)
#pragma unroll
                for (int r = 0; r < 4; r++) {
                    const int m = bm + wm + tm * 16 + quad * 4 + r;
                    const int n = bn + wn + tn * 16 + l16;
                    const int bb = m >> 11, s = m & 2047;
                    const int h = n >> 6, d = n & 63;
                    dst[(((size_t)(bb * Hh + h)) * Sq + s) * HDim + d] = (bf16)acc[tm][tn][r];
                }
    } else {
        // V: transpose the 128x128 output tile in LDS, write VT[bh][d][s]
        __syncthreads();
        bf16 (*CT)[136] = (bf16(*)[136])smem;      // 128x136x2 = 34816 B
#pragma unroll
        for (int tm = 0; tm < 4; tm++)
#pragma unroll
            for (int tn = 0; tn < 4; tn++)
#pragma unroll
                for (int r = 0; r < 4; r++) {
                    const int ml = wm + tm * 16 + quad * 4 + r;
                    const int nl = wn + tn * 16 + l16;
                    CT[nl][ml] = (bf16)acc[tm][tn][r];
                }
        __syncthreads();
        const int nl = tid >> 1, part = tid & 1;
        const int n = bn + nl, h = n >> 6, d = n & 63;
        const int bbv = bm >> 11, s0v = bm & 2047;
        bf16* o = VT + (((size_t)(bbv * Hh + h)) * HDim + d) * Sq + s0v + part * 64;
#pragma unroll
        for (int i = 0; i < 8; i++)
            *(bf16x8*)(o + i * 8) = *(const bf16x8*)&CT[nl][part * 64 + i * 8];
    }
}

// ---------------------------------------------------------------------------
// Kernel 2: flash-style causal attention (per batch-chunk of 2).
// grid = (16 block-pairs, 32 bh).  Each block does q-tiles {x, 31-x}
// (balanced 33 k-iters).  K and V^T staged straight (no LDS transpose).
// ---------------------------------------------------------------------------
__global__ __launch_bounds__(256)
void attn(const bf16* __restrict__ Qb, const bf16* __restrict__ Kb,
          const bf16* __restrict__ VTg, bf16* __restrict__ Cx)
{
    const int bh = blockIdx.y;          // 0..31 local (2 batches x 16 heads)
    const int bl = bh >> 4, h = bh & 15;

    __shared__ __align__(16) bf16 Kl[64][72];     // [key][d]
    __shared__ __align__(16) bf16 Vt[64][72];     // [d][key]
    __shared__ __align__(16) bf16 Pl[4][16][72];

    const int tid  = threadIdx.x;
    const int wave = tid >> 6, lane = tid & 63, quad = lane >> 4, l16 = lane & 15;
    const int sr = tid >> 2, sc = (tid & 3) * 16;

    for (int pass = 0; pass < 2; pass++) {
        const int qt = (pass == 0) ? (int)blockIdx.x : 31 - (int)blockIdx.x;
        const int q0 = qt * 64 + wave * 16;

        const bf16* Qrow = Qb + ((size_t)bh * Sq + q0 + l16) * HDim;
        bf16x8 aq[2];
        aq[0] = *(const bf16x8*)(Qrow + quad * 8);
        aq[1] = *(const bf16x8*)(Qrow + 32 + quad * 8);

        floatx4 acc_o[4];
#pragma unroll
        for (int i = 0; i < 4; i++) acc_o[i] = (floatx4){0.f, 0.f, 0.f, 0.f};
        float m_old[4], l_sum[4];
#pragma unroll
        for (int r = 0; r < 4; r++) { m_old[r] = -1e30f; l_sum[r] = 0.f; }

        for (int kt = 0; kt <= qt; kt++) {
            __syncthreads();
            {   // straight-copy staging: conflict-free b128 writes
                const bf16* ks = Kb + ((size_t)bh * Sq + kt * 64 + sr) * HDim + sc;
                *(bf16x8*)&Kl[sr][sc]     = *(const bf16x8*)ks;
                *(bf16x8*)&Kl[sr][sc + 8] = *(const bf16x8*)(ks + 8);
                const bf16* vs = VTg + ((size_t)bh * HDim + sr) * Sq + kt * 64 + sc;
                *(bf16x8*)&Vt[sr][sc]     = *(const bf16x8*)vs;
                *(bf16x8*)&Vt[sr][sc + 8] = *(const bf16x8*)(vs + 8);
            }
            __syncthreads();

            floatx4 s[4];
#pragma unroll
            for (int tn = 0; tn < 4; tn++) {
                bf16x8 bk0 = *(const bf16x8*)&Kl[tn * 16 + l16][quad * 8];
                bf16x8 bk1 = *(const bf16x8*)&Kl[tn * 16 + l16][32 + quad * 8];
                floatx4 z = (floatx4){0.f, 0.f, 0.f, 0.f};
                z = __builtin_amdgcn_mfma_f32_16x16x32_bf16(aq[0], bk0, z, 0, 0, 0);
                z = __builtin_amdgcn_mfma_f32_16x16x32_bf16(aq[1], bk1, z, 0, 0, 0);
                s[tn] = z;
            }

            if (kt == qt) {
#pragma unroll
                for (int tn = 0; tn < 4; tn++)
#pragma unroll
                    for (int r = 0; r < 4; r++) {
                        const int key  = kt * 64 + tn * 16 + l16;
                        const int qrow = q0 + quad * 4 + r;
                        if (key > qrow) s[tn][r] = -1e30f;
                    }
            }
            const float scale = 0.125f;
#pragma unroll
            for (int tn = 0; tn < 4; tn++)
#pragma unroll
                for (int r = 0; r < 4; r++) s[tn][r] *= scale;

            float p[4][4], alpha[4];
#pragma unroll
            for (int r = 0; r < 4; r++) {
                float mx = fmaxf(fmaxf(s[0][r], s[1][r]), fmaxf(s[2][r], s[3][r]));
#pragma unroll
                for (int off = 8; off >= 1; off >>= 1)
                    mx = fmaxf(mx, __shfl_xor(mx, off, 64));
                const float mn = fmaxf(m_old[r], mx);
                alpha[r] = __expf(m_old[r] - mn);
                m_old[r] = mn;
                float rs = 0.f;
#pragma unroll
                for (int tn = 0; tn < 4; tn++) {
                    const float e = __expf(s[tn][r] - mn);
                    p[tn][r] = e;
                    rs += e;
                }
#pragma unroll
                for (int off = 8; off >= 1; off >>= 1)
                    rs += __shfl_xor(rs, off, 64);
                l_sum[r] = l_sum[r] * alpha[r] + rs;
            }

#pragma unroll
            for (int tn = 0; tn < 4; tn++)
#pragma unroll
                for (int r = 0; r < 4; r++) {
                    Pl[wave][quad * 4 + r][tn * 16 + l16] = (bf16)p[tn][r];
                    acc_o[tn][r] *= alpha[r];
                }
            __syncthreads();

            bf16x8 ap0 = *(const bf16x8*)&Pl[wave][l16][quad * 8];
            bf16x8 ap1 = *(const bf16x8*)&Pl[wave][l16][32 + quad * 8];
#pragma unroll
            for (int tn = 0; tn < 4; tn++) {
                bf16x8 bv0 = *(const bf16x8*)&Vt[tn * 16 + l16][quad * 8];
                bf16x8 bv1 = *(const bf16x8*)&Vt[tn * 16 + l16][32 + quad * 8];
                acc_o[tn] = __builtin_amdgcn_mfma_f32_16x16x32_bf16(ap0, bv0, acc_o[tn], 0, 0, 0);
                acc_o[tn] = __builtin_amdgcn_mfma_f32_16x16x32_bf16(ap1, bv1, acc_o[tn], 0, 0, 0);
            }
        }

#pragma unroll
        for (int tn = 0; tn < 4; tn++)
#pragma unroll
            for (int r = 0; r < 4; r++) {
                const int qrow = q0 + quad * 4 + r;
                const int dcol = tn * 16 + l16;
                const float o = acc_o[tn][r] / l_sum[r];
                Cx[((size_t)(bl * Sq + qrow)) * Dm + h * HDim + dcol] = (bf16)o;
            }
    }
}

// ---------------------------------------------------------------------------
// Kernel 3: output projection (per chunk).  Cx(4096x1024 bf16) @ WoT + bo.
// Both operands DMA-staged into swizzled [128][64] LDS.
// ---------------------------------------------------------------------------
__global__ __launch_bounds__(256, 2)
void out_gemm(const bf16* __restrict__ Cx, const bf16* __restrict__ WtO,
              const float* __restrict__ bo, float* __restrict__ out, int mbase)
{
    __shared__ __align__(16) bf16 As2[128][64];
    __shared__ __align__(16) bf16 Bs2[128][64];

    const int tid  = threadIdx.x;
    const int wave = tid >> 6, lane = tid & 63, quad = lane >> 4, l16 = lane & 15;
    const int bm = blockIdx.y * 128, bn = blockIdx.x * 128;
    const int wm = (wave >> 1) * 64, wn = (wave & 1) * 64;

    floatx4 acc[4][4];
#pragma unroll
    for (int i = 0; i < 4; i++)
#pragma unroll
        for (int j = 0; j < 4; j++) acc[i][j] = (floatx4){0.f, 0.f, 0.f, 0.f};

    for (int k0 = 0; k0 < 1024; k0 += 64) {
        __syncthreads();
#pragma unroll
        for (int i = 0; i < 4; i++) {
            const int row = wave * 32 + i * 8 + (lane >> 3);
            const int lb  = (lane & 7) ^ (row & 7);
            const bf16* ga = Cx  + (size_t)(bm + row) * 1024 + k0 + lb * 8;
            const bf16* gb = WtO + (size_t)(bn + row) * 1024 + k0 + lb * 8;
            dma16((const void*)ga, (void*)&As2[wave * 32 + i * 8][0]);
            dma16((const void*)gb, (void*)&Bs2[wave * 32 + i * 8][0]);
        }
        __syncthreads();

#pragma unroll
        for (int kk = 0; kk < 2; kk++) {
            bf16x8 a[4], b[4];
#pragma unroll
            for (int tm = 0; tm < 4; tm++) {
                const int m = wm + tm * 16 + l16;
                const int phys = (kk * 4 + quad) ^ (m & 7);
                a[tm] = *(const bf16x8*)&As2[m][phys * 8];
            }
#pragma unroll
            for (int tn = 0; tn < 4; tn++) {
                const int n = wn + tn * 16 + l16;
                const int phys = (kk * 4 + quad) ^ (n & 7);
                b[tn] = *(const bf16x8*)&Bs2[n][phys * 8];
            }
#pragma unroll
            for (int tm = 0; tm < 4; tm++)
#pragma unroll
                for (int tn = 0; tn < 4; tn++)
                    acc[tm][tn] = __builtin_amdgcn_mfma_f32_16x16x32_bf16(a[tm], b[tn], acc[tm][tn], 0, 0, 0);
        }
    }

#pragma unroll
    for (int tm = 0; tm < 4; tm++)
#pragma unroll
        for (int tn = 0; tn < 4; tn++)
#pragma unroll
            for (int r = 0; r < 4; r++) {
                const int m = bm + wm + tm * 16 + quad * 4 + r;
                const int n = bn + wn + tn * 16 + l16;
                out[(size_t)(mbase + m) * 1024 + n] = acc[tm][tn][r] + bo[n];
            }
}

// ---------------------------------------------------------------------------
extern "C" void kernel_launch(void* const* d_in, const int* in_sizes, int n_in,
                              void* d_out, int out_size, void* d_ws, size_t ws_size,
                              hipStream_t stream)
{
    const float* x  = (const float*)d_in[0];
    const float* Wq = (const float*)d_in[1];
    const float* Wk = (const float*)d_in[2];
    const float* Wv = (const float*)d_in[3];
    const float* Wo = (const float*)d_in[4];
    const float* bo = (const float*)d_in[5];
    float* out = (float*)d_out;

    // ws layout (64 MB total, proven available in R1):
    // Wt 4x1Mx2B = 8 MB | Qb 16 | Kb 16 | VT 16 | Cx 8
    bf16* Wt = (bf16*)d_ws;
    bf16* Qb = Wt + (size_t)4 * 1024 * 1024;
    bf16* Kb = Qb + (size_t)8 * 1024 * 1024;
    bf16* VT = Kb + (size_t)8 * 1024 * 1024;
    bf16* Cx = VT + (size_t)8 * 1024 * 1024;

    prep_weights<<<dim3(16, 16, 4), 256, 0, stream>>>(Wq, Wk, Wv, Wo, Wt);
    qkv_gemm<<<dim3(8, 64, 3), 256, 0, stream>>>(x, Wt, Qb, Kb, VT);

    const size_t chunk = (size_t)2 * Hh * Sq * HDim;  // 2 batches of Q/K/VT
    for (int c = 0; c < 2; c++) {
        attn<<<dim3(16, 32), 256, 0, stream>>>(Qb + c * chunk, Kb + c * chunk,
                                               VT + c * chunk, Cx);
        out_gemm<<<dim3(8, 32), 256, 0, stream>>>(Cx, Wt + (size_t)3 * 1024 * 1024,
                                                  bo, out, c * 4096);
    }
}

// Round 3
// 315.238 us; speedup vs baseline: 2.7808x; 1.3357x over previous
//
#include <hip/hip_runtime.h>
#include <math.h>
#include <stdint.h>

typedef __bf16 bf16;
typedef bf16 bf16x8 __attribute__((ext_vector_type(8)));
typedef float floatx4 __attribute__((ext_vector_type(4)));

static constexpr int Sq = 2048, Dm = 1024, Hh = 16, HDim = 64;

#define GAS __attribute__((address_space(1)))
#define LAS __attribute__((address_space(3)))

// async global->LDS DMA, 16 B per lane; lds base wave-uniform, lane i -> base + i*16
__device__ __forceinline__ void dma16(const void* g, void* l) {
    __builtin_amdgcn_global_load_lds((const GAS void*)g, (LAS void*)l, 16, 0, 0);
}

__device__ __forceinline__ uint32_t pk_bf16(float a, float b) {
    unsigned short lo = __builtin_bit_cast(unsigned short, (bf16)a);
    unsigned short hi = __builtin_bit_cast(unsigned short, (bf16)b);
    return (uint32_t)lo | ((uint32_t)hi << 16);
}

// ---------------------------------------------------------------------------
// Kernel A: x fp32 -> bf16 (one pass).  8 elems/thread.
// ---------------------------------------------------------------------------
__global__ __launch_bounds__(256)
void conv_x(const float* __restrict__ x, bf16* __restrict__ xb)
{
    const size_t i = ((size_t)blockIdx.x * 256 + threadIdx.x) * 8;
    float4 f0 = *(const float4*)(x + i);
    float4 f1 = *(const float4*)(x + i + 4);
    bf16x8 v;
    v[0]=(bf16)f0.x; v[1]=(bf16)f0.y; v[2]=(bf16)f0.z; v[3]=(bf16)f0.w;
    v[4]=(bf16)f1.x; v[5]=(bf16)f1.y; v[6]=(bf16)f1.z; v[7]=(bf16)f1.w;
    *(bf16x8*)(xb + i) = v;
}

// ---------------------------------------------------------------------------
// Kernel 0: weight prep.  W fp32 [k][n] -> Wt bf16 [n][k], 4 matrices.
// ---------------------------------------------------------------------------
__global__ __launch_bounds__(256)
void prep_weights(const float* __restrict__ Wq, const float* __restrict__ Wk,
                  const float* __restrict__ Wv, const float* __restrict__ Wo,
                  bf16* __restrict__ Wt)
{
    const int w = blockIdx.z;
    const float* W = (w == 0) ? Wq : (w == 1) ? Wk : (w == 2) ? Wv : Wo;
    bf16* dst = Wt + (size_t)w * 1024 * 1024;
    const int k0 = blockIdx.x * 64, n0 = blockIdx.y * 64;
    __shared__ uint32_t Tl[64][33];
    const int t = threadIdx.x;
    {
        const int c8 = (t & 7) * 8;
        const int kp = t >> 3;
        const float* r0 = W + (size_t)(k0 + 2 * kp) * 1024 + n0 + c8;
        const float* r1 = r0 + 1024;
        float4 a0 = *(const float4*)r0, a1 = *(const float4*)(r0 + 4);
        float4 b0 = *(const float4*)r1, b1 = *(const float4*)(r1 + 4);
        float ra[8] = {a0.x, a0.y, a0.z, a0.w, a1.x, a1.y, a1.z, a1.w};
        float rb[8] = {b0.x, b0.y, b0.z, b0.w, b1.x, b1.y, b1.z, b1.w};
#pragma unroll
        for (int j = 0; j < 8; j++)
            Tl[c8 + j][kp] = pk_bf16(ra[j], rb[j]);
    }
    __syncthreads();
    {
        const int c = t >> 2, dq = (t & 3) * 8;
        uint32_t d[8];
#pragma unroll
        for (int i = 0; i < 8; i++) d[i] = Tl[c][dq + i];
        uint32_t* o = (uint32_t*)(dst + (size_t)(n0 + c) * 1024 + k0 + dq * 2);
        *(uint4*)o       = make_uint4(d[0], d[1], d[2], d[3]);
        *(uint4*)(o + 4) = make_uint4(d[4], d[5], d[6], d[7]);
    }
}

// ---------------------------------------------------------------------------
// Kernel 1: QKV projection.  AMODE=1: bf16 xb via DMA (primary);
// AMODE=0: fp32 x via register convert (fallback).  128x128 tile, BK=64.
// ---------------------------------------------------------------------------
template <int AMODE>
__global__ __launch_bounds__(256, 2)
void qkv_gemm(const float* __restrict__ x, const bf16* __restrict__ xb,
              const bf16* __restrict__ Wt,
              bf16* __restrict__ Qb, bf16* __restrict__ Kb, bf16* __restrict__ VT)
{
    const int zz = blockIdx.z;
    const bf16* Wsel = Wt + (size_t)zz * 1024 * 1024;

    __shared__ __align__(16) unsigned char smem[34816];
    // AMODE=1: As [128][64] swizzled @0, Bs @16384
    // AMODE=0: As [128][72] padded  @0, Bs @18432
    bf16 (*As1)[64] = (bf16(*)[64])smem;
    bf16 (*As0)[72] = (bf16(*)[72])smem;
    bf16 (*Bs)[64]  = (bf16(*)[64])(smem + (AMODE ? 16384 : 18432));

    const int tid  = threadIdx.x;
    const int wave = tid >> 6, lane = tid & 63, quad = lane >> 4, l16 = lane & 15;
    const int bm = blockIdx.y * 128, bn = blockIdx.x * 128;
    const int wm = (wave >> 1) * 64, wn = (wave & 1) * 64;

    floatx4 acc[4][4];
#pragma unroll
    for (int i = 0; i < 4; i++)
#pragma unroll
        for (int j = 0; j < 4; j++) acc[i][j] = (floatx4){0.f, 0.f, 0.f, 0.f};

    for (int k0 = 0; k0 < 1024; k0 += 64) {
        __syncthreads();
#pragma unroll
        for (int i = 0; i < 4; i++) {
            const int row = wave * 32 + i * 8 + (lane >> 3);
            const int lb  = (lane & 7) ^ (row & 7);
            const bf16* g = Wsel + (size_t)(bn + row) * 1024 + k0 + lb * 8;
            dma16((const void*)g, (void*)&Bs[wave * 32 + i * 8][0]);
        }
        if (AMODE) {
#pragma unroll
            for (int i = 0; i < 4; i++) {
                const int row = wave * 32 + i * 8 + (lane >> 3);
                const int lb  = (lane & 7) ^ (row & 7);
                const bf16* g = xb + (size_t)(bm + row) * 1024 + k0 + lb * 8;
                dma16((const void*)g, (void*)&As1[wave * 32 + i * 8][0]);
            }
        } else {
#pragma unroll
            for (int it = 0; it < 2; it++) {
                const int r  = (tid >> 2) + it * 64;
                const int cq = (tid & 3) * 16;
                const float* src = x + (size_t)(bm + r) * 1024 + k0 + cq;
                float4 f0 = *(const float4*)src,       f1 = *(const float4*)(src + 4);
                float4 f2 = *(const float4*)(src + 8), f3 = *(const float4*)(src + 12);
                bf16x8 v0, v1;
                v0[0]=(bf16)f0.x; v0[1]=(bf16)f0.y; v0[2]=(bf16)f0.z; v0[3]=(bf16)f0.w;
                v0[4]=(bf16)f1.x; v0[5]=(bf16)f1.y; v0[6]=(bf16)f1.z; v0[7]=(bf16)f1.w;
                v1[0]=(bf16)f2.x; v1[1]=(bf16)f2.y; v1[2]=(bf16)f2.z; v1[3]=(bf16)f2.w;
                v1[4]=(bf16)f3.x; v1[5]=(bf16)f3.y; v1[6]=(bf16)f3.z; v1[7]=(bf16)f3.w;
                *(bf16x8*)&As0[r][cq]     = v0;
                *(bf16x8*)&As0[r][cq + 8] = v1;
            }
        }
        __syncthreads();

#pragma unroll
        for (int kk = 0; kk < 2; kk++) {
            bf16x8 a[4], b[4];
#pragma unroll
            for (int tm = 0; tm < 4; tm++) {
                const int m = wm + tm * 16 + l16;
                if (AMODE) {
                    const int phys = (kk * 4 + quad) ^ (m & 7);
                    a[tm] = *(const bf16x8*)&As1[m][phys * 8];
                } else {
                    a[tm] = *(const bf16x8*)&As0[m][kk * 32 + quad * 8];
                }
            }
#pragma unroll
            for (int tn = 0; tn < 4; tn++) {
                const int n = wn + tn * 16 + l16;
                const int phys = (kk * 4 + quad) ^ (n & 7);
                b[tn] = *(const bf16x8*)&Bs[n][phys * 8];
            }
#pragma unroll
            for (int tm = 0; tm < 4; tm++)
#pragma unroll
                for (int tn = 0; tn < 4; tn++)
                    acc[tm][tn] = __builtin_amdgcn_mfma_f32_16x16x32_bf16(a[tm], b[tn], acc[tm][tn], 0, 0, 0);
        }
    }

    if (zz < 2) {
        bf16* dst = (zz == 0) ? Qb : Kb;
#pragma unroll
        for (int tm = 0; tm < 4; tm++)
#pragma unroll
            for (int tn = 0; tn < 4; tn++)
#pragma unroll
                for (int r = 0; r < 4; r++) {
                    const int m = bm + wm + tm * 16 + quad * 4 + r;
                    const int n = bn + wn + tn * 16 + l16;
                    const int bb = m >> 11, s = m & 2047;
                    const int h = n >> 6, d = n & 63;
                    dst[(((size_t)(bb * Hh + h)) * Sq + s) * HDim + d] = (bf16)acc[tm][tn][r];
                }
    } else {
        // V: transpose 128x128 tile in LDS -> VT[bh][d][s]
        __syncthreads();
        bf16 (*CT)[136] = (bf16(*)[136])smem;
#pragma unroll
        for (int tm = 0; tm < 4; tm++)
#pragma unroll
            for (int tn = 0; tn < 4; tn++)
#pragma unroll
                for (int r = 0; r < 4; r++) {
                    const int ml = wm + tm * 16 + quad * 4 + r;
                    const int nl = wn + tn * 16 + l16;
                    CT[nl][ml] = (bf16)acc[tm][tn][r];
                }
        __syncthreads();
        const int nl = tid >> 1, part = tid & 1;
        const int n = bn + nl, h = n >> 6, d = n & 63;
        const int bbv = bm >> 11, s0v = bm & 2047;
        bf16* o = VT + (((size_t)(bbv * Hh + h)) * HDim + d) * Sq + s0v + part * 64;
#pragma unroll
        for (int i = 0; i < 8; i++)
            *(bf16x8*)(o + i * 8) = *(const bf16x8*)&CT[nl][part * 64 + i * 8];
    }
}

// ---------------------------------------------------------------------------
// Kernel 2: flash-style causal attention.  grid = (16, nbh).  Each block does
// q-tiles {x, 31-x}.  K and V^T DMA-staged into swizzled [64][64] LDS.
// ---------------------------------------------------------------------------
__global__ __launch_bounds__(256)
void attn(const bf16* __restrict__ Qb, const bf16* __restrict__ Kb,
          const bf16* __restrict__ VTg, bf16* __restrict__ Cx)
{
    const int bh = blockIdx.y;
    const int bl = bh >> 4, h = bh & 15;

    __shared__ __align__(16) bf16 Kl[64][64];     // [key][d], 16B-swizzled
    __shared__ __align__(16) bf16 Vt[64][64];     // [d][key], 16B-swizzled
    __shared__ __align__(16) bf16 Pl[4][16][72];

    const int tid  = threadIdx.x;
    const int wave = tid >> 6, lane = tid & 63, quad = lane >> 4, l16 = lane & 15;

    for (int pass = 0; pass < 2; pass++) {
        const int qt = (pass == 0) ? (int)blockIdx.x : 31 - (int)blockIdx.x;
        const int q0 = qt * 64 + wave * 16;

        const bf16* Qrow = Qb + ((size_t)bh * Sq + q0 + l16) * HDim;
        bf16x8 aq[2];
        aq[0] = *(const bf16x8*)(Qrow + quad * 8);
        aq[1] = *(const bf16x8*)(Qrow + 32 + quad * 8);

        floatx4 acc_o[4];
#pragma unroll
        for (int i = 0; i < 4; i++) acc_o[i] = (floatx4){0.f, 0.f, 0.f, 0.f};
        float m_old[4], l_sum[4];
#pragma unroll
        for (int r = 0; r < 4; r++) { m_old[r] = -1e30f; l_sum[r] = 0.f; }

        for (int kt = 0; kt <= qt; kt++) {
            __syncthreads();
            // DMA staging: per wave 2 issues K + 2 issues VT (8 rows each)
#pragma unroll
            for (int i = 0; i < 2; i++) {
                const int row = wave * 16 + i * 8 + (lane >> 3);
                const int lb  = (lane & 7) ^ (row & 7);
                const bf16* ks = Kb + ((size_t)bh * Sq + kt * 64 + row) * HDim + lb * 8;
                dma16((const void*)ks, (void*)&Kl[wave * 16 + i * 8][0]);
                const bf16* vs = VTg + ((size_t)bh * HDim + row) * Sq + kt * 64 + lb * 8;
                dma16((const void*)vs, (void*)&Vt[wave * 16 + i * 8][0]);
            }
            __syncthreads();

            floatx4 s[4];
#pragma unroll
            for (int tn = 0; tn < 4; tn++) {
                const int kr = tn * 16 + l16;
                bf16x8 bk0 = *(const bf16x8*)&Kl[kr][(quad ^ (kr & 7)) * 8];
                bf16x8 bk1 = *(const bf16x8*)&Kl[kr][((4 + quad) ^ (kr & 7)) * 8];
                floatx4 z = (floatx4){0.f, 0.f, 0.f, 0.f};
                z = __builtin_amdgcn_mfma_f32_16x16x32_bf16(aq[0], bk0, z, 0, 0, 0);
                z = __builtin_amdgcn_mfma_f32_16x16x32_bf16(aq[1], bk1, z, 0, 0, 0);
                s[tn] = z;
            }

            if (kt == qt) {
#pragma unroll
                for (int tn = 0; tn < 4; tn++)
#pragma unroll
                    for (int r = 0; r < 4; r++) {
                        const int key  = kt * 64 + tn * 16 + l16;
                        const int qrow = q0 + quad * 4 + r;
                        if (key > qrow) s[tn][r] = -1e30f;
                    }
            }
            const float scale = 0.125f;
#pragma unroll
            for (int tn = 0; tn < 4; tn++)
#pragma unroll
                for (int r = 0; r < 4; r++) s[tn][r] *= scale;

            float p[4][4], alpha[4];
#pragma unroll
            for (int r = 0; r < 4; r++) {
                float mx = fmaxf(fmaxf(s[0][r], s[1][r]), fmaxf(s[2][r], s[3][r]));
#pragma unroll
                for (int off = 8; off >= 1; off >>= 1)
                    mx = fmaxf(mx, __shfl_xor(mx, off, 64));
                const float mn = fmaxf(m_old[r], mx);
                alpha[r] = __expf(m_old[r] - mn);
                m_old[r] = mn;
                float rs = 0.f;
#pragma unroll
                for (int tn = 0; tn < 4; tn++) {
                    const float e = __expf(s[tn][r] - mn);
                    p[tn][r] = e;
                    rs += e;
                }
#pragma unroll
                for (int off = 8; off >= 1; off >>= 1)
                    rs += __shfl_xor(rs, off, 64);
                l_sum[r] = l_sum[r] * alpha[r] + rs;
            }

#pragma unroll
            for (int tn = 0; tn < 4; tn++)
#pragma unroll
                for (int r = 0; r < 4; r++) {
                    Pl[wave][quad * 4 + r][tn * 16 + l16] = (bf16)p[tn][r];
                    acc_o[tn][r] *= alpha[r];
                }
            __syncthreads();

            bf16x8 ap0 = *(const bf16x8*)&Pl[wave][l16][quad * 8];
            bf16x8 ap1 = *(const bf16x8*)&Pl[wave][l16][32 + quad * 8];
#pragma unroll
            for (int tn = 0; tn < 4; tn++) {
                const int vr = tn * 16 + l16;
                bf16x8 bv0 = *(const bf16x8*)&Vt[vr][(quad ^ (vr & 7)) * 8];
                bf16x8 bv1 = *(const bf16x8*)&Vt[vr][((4 + quad) ^ (vr & 7)) * 8];
                acc_o[tn] = __builtin_amdgcn_mfma_f32_16x16x32_bf16(ap0, bv0, acc_o[tn], 0, 0, 0);
                acc_o[tn] = __builtin_amdgcn_mfma_f32_16x16x32_bf16(ap1, bv1, acc_o[tn], 0, 0, 0);
            }
        }

#pragma unroll
        for (int tn = 0; tn < 4; tn++)
#pragma unroll
            for (int r = 0; r < 4; r++) {
                const int qrow = q0 + quad * 4 + r;
                const int dcol = tn * 16 + l16;
                const float o = acc_o[tn][r] / l_sum[r];
                Cx[((size_t)(bl * Sq + qrow)) * Dm + h * HDim + dcol] = (bf16)o;
            }
    }
}

// ---------------------------------------------------------------------------
// Kernel 3: output projection.  Cx bf16 @ WoT + bo -> fp32 out.
// ---------------------------------------------------------------------------
__global__ __launch_bounds__(256, 2)
void out_gemm(const bf16* __restrict__ Cx, const bf16* __restrict__ WtO,
              const float* __restrict__ bo, float* __restrict__ out, int mbase)
{
    __shared__ __align__(16) bf16 As2[128][64];
    __shared__ __align__(16) bf16 Bs2[128][64];

    const int tid  = threadIdx.x;
    const int wave = tid >> 6, lane = tid & 63, quad = lane >> 4, l16 = lane & 15;
    const int bm = blockIdx.y * 128, bn = blockIdx.x * 128;
    const int wm = (wave >> 1) * 64, wn = (wave & 1) * 64;

    floatx4 acc[4][4];
#pragma unroll
    for (int i = 0; i < 4; i++)
#pragma unroll
        for (int j = 0; j < 4; j++) acc[i][j] = (floatx4){0.f, 0.f, 0.f, 0.f};

    for (int k0 = 0; k0 < 1024; k0 += 64) {
        __syncthreads();
#pragma unroll
        for (int i = 0; i < 4; i++) {
            const int row = wave * 32 + i * 8 + (lane >> 3);
            const int lb  = (lane & 7) ^ (row & 7);
            const bf16* ga = Cx  + (size_t)(bm + row) * 1024 + k0 + lb * 8;
            const bf16* gb = WtO + (size_t)(bn + row) * 1024 + k0 + lb * 8;
            dma16((const void*)ga, (void*)&As2[wave * 32 + i * 8][0]);
            dma16((const void*)gb, (void*)&Bs2[wave * 32 + i * 8][0]);
        }
        __syncthreads();

#pragma unroll
        for (int kk = 0; kk < 2; kk++) {
            bf16x8 a[4], b[4];
#pragma unroll
            for (int tm = 0; tm < 4; tm++) {
                const int m = wm + tm * 16 + l16;
                const int phys = (kk * 4 + quad) ^ (m & 7);
                a[tm] = *(const bf16x8*)&As2[m][phys * 8];
            }
#pragma unroll
            for (int tn = 0; tn < 4; tn++) {
                const int n = wn + tn * 16 + l16;
                const int phys = (kk * 4 + quad) ^ (n & 7);
                b[tn] = *(const bf16x8*)&Bs2[n][phys * 8];
            }
#pragma unroll
            for (int tm = 0; tm < 4; tm++)
#pragma unroll
                for (int tn = 0; tn < 4; tn++)
                    acc[tm][tn] = __builtin_amdgcn_mfma_f32_16x16x32_bf16(a[tm], b[tn], acc[tm][tn], 0, 0, 0);
        }
    }

#pragma unroll
    for (int tm = 0; tm < 4; tm++)
#pragma unroll
        for (int tn = 0; tn < 4; tn++)
#pragma unroll
            for (int r = 0; r < 4; r++) {
                const int m = bm + wm + tm * 16 + quad * 4 + r;
                const int n = bn + wn + tn * 16 + l16;
                out[(size_t)(mbase + m) * 1024 + n] = acc[tm][tn][r] + bo[n];
            }
}

// ---------------------------------------------------------------------------
extern "C" void kernel_launch(void* const* d_in, const int* in_sizes, int n_in,
                              void* d_out, int out_size, void* d_ws, size_t ws_size,
                              hipStream_t stream)
{
    const float* x  = (const float*)d_in[0];
    const float* Wq = (const float*)d_in[1];
    const float* Wk = (const float*)d_in[2];
    const float* Wv = (const float*)d_in[3];
    const float* Wo = (const float*)d_in[4];
    const float* bo = (const float*)d_in[5];
    float* out = (float*)d_out;

    const size_t M1 = 1024 * 1024;        // 1M elems
    const size_t XE = (size_t)8192 * 1024; // 8M elems

    if (ws_size >= (size_t)72 * 1024 * 1024) {
        // primary: Wt 8MB | xb 16 (aliased by Cx) | Qb 16 | Kb 16 | VT 16
        bf16* Wt = (bf16*)d_ws;
        bf16* xb = Wt + 4 * M1;
        bf16* Qb = xb + XE;
        bf16* Kb = Qb + XE;
        bf16* VT = Kb + XE;
        bf16* Cx = xb;  // alias: xb dead after qkv_gemm

        conv_x<<<dim3(4096), 256, 0, stream>>>(x, xb);
        prep_weights<<<dim3(16, 16, 4), 256, 0, stream>>>(Wq, Wk, Wv, Wo, Wt);
        qkv_gemm<1><<<dim3(8, 64, 3), 256, 0, stream>>>(x, xb, Wt, Qb, Kb, VT);
        attn<<<dim3(16, 64), 256, 0, stream>>>(Qb, Kb, VT, Cx);
        out_gemm<<<dim3(8, 64), 256, 0, stream>>>(Cx, Wt + 3 * M1, bo, out, 0);
    } else {
        // fallback (64 MB, R2-proven): Wt 8 | Qb 16 | Kb 16 | VT 16 | Cx 8
        bf16* Wt = (bf16*)d_ws;
        bf16* Qb = Wt + 4 * M1;
        bf16* Kb = Qb + XE;
        bf16* VT = Kb + XE;
        bf16* Cx = VT + XE;

        prep_weights<<<dim3(16, 16, 4), 256, 0, stream>>>(Wq, Wk, Wv, Wo, Wt);
        qkv_gemm<0><<<dim3(8, 64, 3), 256, 0, stream>>>(x, nullptr, Wt, Qb, Kb, VT);
        const size_t chunk = (size_t)2 * Hh * Sq * HDim;
        for (int c = 0; c < 2; c++) {
            attn<<<dim3(16, 32), 256, 0, stream>>>(Qb + c * chunk, Kb + c * chunk,
                                                   VT + c * chunk, Cx);
            out_gemm<<<dim3(8, 32), 256, 0, stream>>>(Cx, Wt + 3 * M1, bo, out, c * 4096);
        }
    }
}

// Round 4
// 286.734 us; speedup vs baseline: 3.0572x; 1.0994x over previous
//
#include <hip/hip_runtime.h>
#include <math.h>
#include <stdint.h>

typedef __bf16 bf16;
typedef bf16 bf16x8 __attribute__((ext_vector_type(8)));
typedef float floatx4 __attribute__((ext_vector_type(4)));

static constexpr int Sq = 2048, Dm = 1024, Hh = 16, HDim = 64;

#define GAS __attribute__((address_space(1)))
#define LAS __attribute__((address_space(3)))

// async global->LDS DMA, 16 B per lane; lds base wave-uniform, lane i -> base + i*16
__device__ __forceinline__ void dma16(const void* g, void* l) {
    __builtin_amdgcn_global_load_lds((const GAS void*)g, (LAS void*)l, 16, 0, 0);
}

__device__ __forceinline__ uint32_t pk_bf16(float a, float b) {
    unsigned short lo = __builtin_bit_cast(unsigned short, (bf16)a);
    unsigned short hi = __builtin_bit_cast(unsigned short, (bf16)b);
    return (uint32_t)lo | ((uint32_t)hi << 16);
}

// ---------------------------------------------------------------------------
// Kernel A: x fp32 -> bf16 (one pass).  8 elems/thread.
// ---------------------------------------------------------------------------
__global__ __launch_bounds__(256)
void conv_x(const float* __restrict__ x, bf16* __restrict__ xb)
{
    const size_t i = ((size_t)blockIdx.x * 256 + threadIdx.x) * 8;
    float4 f0 = *(const float4*)(x + i);
    float4 f1 = *(const float4*)(x + i + 4);
    bf16x8 v;
    v[0]=(bf16)f0.x; v[1]=(bf16)f0.y; v[2]=(bf16)f0.z; v[3]=(bf16)f0.w;
    v[4]=(bf16)f1.x; v[5]=(bf16)f1.y; v[6]=(bf16)f1.z; v[7]=(bf16)f1.w;
    *(bf16x8*)(xb + i) = v;
}

// ---------------------------------------------------------------------------
// Kernel 0: weight prep.  W fp32 [k][n] -> Wt bf16 [n][k], 4 matrices.
// ---------------------------------------------------------------------------
__global__ __launch_bounds__(256)
void prep_weights(const float* __restrict__ Wq, const float* __restrict__ Wk,
                  const float* __restrict__ Wv, const float* __restrict__ Wo,
                  bf16* __restrict__ Wt)
{
    const int w = blockIdx.z;
    const float* W = (w == 0) ? Wq : (w == 1) ? Wk : (w == 2) ? Wv : Wo;
    bf16* dst = Wt + (size_t)w * 1024 * 1024;
    const int k0 = blockIdx.x * 64, n0 = blockIdx.y * 64;
    __shared__ uint32_t Tl[64][33];
    const int t = threadIdx.x;
    {
        const int c8 = (t & 7) * 8;
        const int kp = t >> 3;
        const float* r0 = W + (size_t)(k0 + 2 * kp) * 1024 + n0 + c8;
        const float* r1 = r0 + 1024;
        float4 a0 = *(const float4*)r0, a1 = *(const float4*)(r0 + 4);
        float4 b0 = *(const float4*)r1, b1 = *(const float4*)(r1 + 4);
        float ra[8] = {a0.x, a0.y, a0.z, a0.w, a1.x, a1.y, a1.z, a1.w};
        float rb[8] = {b0.x, b0.y, b0.z, b0.w, b1.x, b1.y, b1.z, b1.w};
#pragma unroll
        for (int j = 0; j < 8; j++)
            Tl[c8 + j][kp] = pk_bf16(ra[j], rb[j]);
    }
    __syncthreads();
    {
        const int c = t >> 2, dq = (t & 3) * 8;
        uint32_t d[8];
#pragma unroll
        for (int i = 0; i < 8; i++) d[i] = Tl[c][dq + i];
        uint32_t* o = (uint32_t*)(dst + (size_t)(n0 + c) * 1024 + k0 + dq * 2);
        *(uint4*)o       = make_uint4(d[0], d[1], d[2], d[3]);
        *(uint4*)(o + 4) = make_uint4(d[4], d[5], d[6], d[7]);
    }
}

// ---------------------------------------------------------------------------
// Kernel 1: QKV projection.  AMODE=1: bf16 xb via DMA (primary);
// AMODE=0: fp32 x (fallback).  128x128 tile, BK=64.
// K output is pre-scaled by 0.125 (= 1/sqrt(HD), exact in bf16).
// ---------------------------------------------------------------------------
template <int AMODE>
__global__ __launch_bounds__(256, 2)
void qkv_gemm(const float* __restrict__ x, const bf16* __restrict__ xb,
              const bf16* __restrict__ Wt,
              bf16* __restrict__ Qb, bf16* __restrict__ Kb, bf16* __restrict__ VT)
{
    const int zz = blockIdx.z;
    const bf16* Wsel = Wt + (size_t)zz * 1024 * 1024;

    __shared__ __align__(16) unsigned char smem[34816];
    bf16 (*As1)[64] = (bf16(*)[64])smem;
    bf16 (*As0)[72] = (bf16(*)[72])smem;
    bf16 (*Bs)[64]  = (bf16(*)[64])(smem + (AMODE ? 16384 : 18432));

    const int tid  = threadIdx.x;
    const int wave = tid >> 6, lane = tid & 63, quad = lane >> 4, l16 = lane & 15;
    const int bm = blockIdx.y * 128, bn = blockIdx.x * 128;
    const int wm = (wave >> 1) * 64, wn = (wave & 1) * 64;

    floatx4 acc[4][4];
#pragma unroll
    for (int i = 0; i < 4; i++)
#pragma unroll
        for (int j = 0; j < 4; j++) acc[i][j] = (floatx4){0.f, 0.f, 0.f, 0.f};

    for (int k0 = 0; k0 < 1024; k0 += 64) {
        __syncthreads();
#pragma unroll
        for (int i = 0; i < 4; i++) {
            const int row = wave * 32 + i * 8 + (lane >> 3);
            const int lb  = (lane & 7) ^ (row & 7);
            const bf16* g = Wsel + (size_t)(bn + row) * 1024 + k0 + lb * 8;
            dma16((const void*)g, (void*)&Bs[wave * 32 + i * 8][0]);
        }
        if (AMODE) {
#pragma unroll
            for (int i = 0; i < 4; i++) {
                const int row = wave * 32 + i * 8 + (lane >> 3);
                const int lb  = (lane & 7) ^ (row & 7);
                const bf16* g = xb + (size_t)(bm + row) * 1024 + k0 + lb * 8;
                dma16((const void*)g, (void*)&As1[wave * 32 + i * 8][0]);
            }
        } else {
#pragma unroll
            for (int it = 0; it < 2; it++) {
                const int r  = (tid >> 2) + it * 64;
                const int cq = (tid & 3) * 16;
                const float* src = x + (size_t)(bm + r) * 1024 + k0 + cq;
                float4 f0 = *(const float4*)src,       f1 = *(const float4*)(src + 4);
                float4 f2 = *(const float4*)(src + 8), f3 = *(const float4*)(src + 12);
                bf16x8 v0, v1;
                v0[0]=(bf16)f0.x; v0[1]=(bf16)f0.y; v0[2]=(bf16)f0.z; v0[3]=(bf16)f0.w;
                v0[4]=(bf16)f1.x; v0[5]=(bf16)f1.y; v0[6]=(bf16)f1.z; v0[7]=(bf16)f1.w;
                v1[0]=(bf16)f2.x; v1[1]=(bf16)f2.y; v1[2]=(bf16)f2.z; v1[3]=(bf16)f2.w;
                v1[4]=(bf16)f3.x; v1[5]=(bf16)f3.y; v1[6]=(bf16)f3.z; v1[7]=(bf16)f3.w;
                *(bf16x8*)&As0[r][cq]     = v0;
                *(bf16x8*)&As0[r][cq + 8] = v1;
            }
        }
        __syncthreads();

#pragma unroll
        for (int kk = 0; kk < 2; kk++) {
            bf16x8 a[4], b[4];
#pragma unroll
            for (int tm = 0; tm < 4; tm++) {
                const int m = wm + tm * 16 + l16;
                if (AMODE) {
                    const int phys = (kk * 4 + quad) ^ (m & 7);
                    a[tm] = *(const bf16x8*)&As1[m][phys * 8];
                } else {
                    a[tm] = *(const bf16x8*)&As0[m][kk * 32 + quad * 8];
                }
            }
#pragma unroll
            for (int tn = 0; tn < 4; tn++) {
                const int n = wn + tn * 16 + l16;
                const int phys = (kk * 4 + quad) ^ (n & 7);
                b[tn] = *(const bf16x8*)&Bs[n][phys * 8];
            }
#pragma unroll
            for (int tm = 0; tm < 4; tm++)
#pragma unroll
                for (int tn = 0; tn < 4; tn++)
                    acc[tm][tn] = __builtin_amdgcn_mfma_f32_16x16x32_bf16(a[tm], b[tn], acc[tm][tn], 0, 0, 0);
        }
    }

    if (zz < 2) {
        bf16* dst = (zz == 0) ? Qb : Kb;
        const float sc = (zz == 1) ? 0.125f : 1.0f;   // fold 1/sqrt(64) into K
#pragma unroll
        for (int tm = 0; tm < 4; tm++)
#pragma unroll
            for (int tn = 0; tn < 4; tn++)
#pragma unroll
                for (int r = 0; r < 4; r++) {
                    const int m = bm + wm + tm * 16 + quad * 4 + r;
                    const int n = bn + wn + tn * 16 + l16;
                    const int bb = m >> 11, s = m & 2047;
                    const int h = n >> 6, d = n & 63;
                    dst[(((size_t)(bb * Hh + h)) * Sq + s) * HDim + d] = (bf16)(acc[tm][tn][r] * sc);
                }
    } else {
        __syncthreads();
        bf16 (*CT)[136] = (bf16(*)[136])smem;
#pragma unroll
        for (int tm = 0; tm < 4; tm++)
#pragma unroll
            for (int tn = 0; tn < 4; tn++)
#pragma unroll
                for (int r = 0; r < 4; r++) {
                    const int ml = wm + tm * 16 + quad * 4 + r;
                    const int nl = wn + tn * 16 + l16;
                    CT[nl][ml] = (bf16)acc[tm][tn][r];
                }
        __syncthreads();
        const int nl = tid >> 1, part = tid & 1;
        const int n = bn + nl, h = n >> 6, d = n & 63;
        const int bbv = bm >> 11, s0v = bm & 2047;
        bf16* o = VT + (((size_t)(bbv * Hh + h)) * HDim + d) * Sq + s0v + part * 64;
#pragma unroll
        for (int i = 0; i < 8; i++)
            *(bf16x8*)(o + i * 8) = *(const bf16x8*)&CT[nl][part * 64 + i * 8];
    }
}

// ---------------------------------------------------------------------------
// Kernel 2: flash-style causal attention, S-TRANSPOSED formulation.
// grid = (8, nbh).  Each block does 128-row q-tiles {x, 15-x} (uniform 34
// k-iters).  Per wave: 32 q-rows.  S^T = K·Q^T (softmax rows become lane
// columns: in-register reduce + 2 shuffles).  O^T = V^T·P^T.
// ---------------------------------------------------------------------------
__global__ __launch_bounds__(256)
void attn(const bf16* __restrict__ Qb, const bf16* __restrict__ Kb,
          const bf16* __restrict__ VTg, bf16* __restrict__ Cx)
{
    const int bh = blockIdx.y;
    const int bl = bh >> 4, h = bh & 15;

    __shared__ __align__(16) bf16 Kl[64][64];      // [key][d], 16B-swizzled
    __shared__ __align__(16) bf16 Vt[64][64];      // [d][key], 16B-swizzled
    __shared__ __align__(16) bf16 PlT[4][32][72];  // per-wave P^T: [qrow][key]

    const int tid  = threadIdx.x;
    const int wave = tid >> 6, lane = tid & 63, quad = lane >> 4, l16 = lane & 15;

    for (int pass = 0; pass < 2; pass++) {
        const int qt = (pass == 0) ? (int)blockIdx.x : 15 - (int)blockIdx.x;
        const int q0 = qt * 128 + wave * 32;        // wave's first q-row

        // Q^T B-fragments: bq[nt][ks] = B[k=hd][n=qrow]
        bf16x8 bq[2][2];
#pragma unroll
        for (int nt = 0; nt < 2; nt++) {
            const bf16* Qrow = Qb + ((size_t)bh * Sq + q0 + nt * 16 + l16) * HDim;
            bq[nt][0] = *(const bf16x8*)(Qrow + quad * 8);
            bq[nt][1] = *(const bf16x8*)(Qrow + 32 + quad * 8);
        }

        floatx4 acc[4][2];   // O^T: [d-tile][q-tile]
#pragma unroll
        for (int i = 0; i < 4; i++)
#pragma unroll
            for (int j = 0; j < 2; j++) acc[i][j] = (floatx4){0.f, 0.f, 0.f, 0.f};
        float m_old[2] = {-1e30f, -1e30f}, l_sum[2] = {0.f, 0.f};

        const int nk = 2 * qt + 2;
        for (int kt = 0; kt < nk; kt++) {
            __syncthreads();
#pragma unroll
            for (int i = 0; i < 2; i++) {
                const int row = wave * 16 + i * 8 + (lane >> 3);
                const int lb  = (lane & 7) ^ (row & 7);
                const bf16* ks = Kb + ((size_t)bh * Sq + kt * 64 + row) * HDim + lb * 8;
                dma16((const void*)ks, (void*)&Kl[wave * 16 + i * 8][0]);
                const bf16* vs = VTg + ((size_t)bh * HDim + row) * Sq + kt * 64 + lb * 8;
                dma16((const void*)vs, (void*)&Vt[wave * 16 + i * 8][0]);
            }
            __syncthreads();

            // S^T[key][qrow] = K · Q^T   (K already scaled by 0.125)
            floatx4 sT[4][2];
#pragma unroll
            for (int mt = 0; mt < 4; mt++) {
                const int kr = mt * 16 + l16;
                bf16x8 ak0 = *(const bf16x8*)&Kl[kr][(quad ^ (kr & 7)) * 8];
                bf16x8 ak1 = *(const bf16x8*)&Kl[kr][((4 + quad) ^ (kr & 7)) * 8];
#pragma unroll
                for (int nt = 0; nt < 2; nt++) {
                    floatx4 z = (floatx4){0.f, 0.f, 0.f, 0.f};
                    z = __builtin_amdgcn_mfma_f32_16x16x32_bf16(ak0, bq[nt][0], z, 0, 0, 0);
                    z = __builtin_amdgcn_mfma_f32_16x16x32_bf16(ak1, bq[nt][1], z, 0, 0, 0);
                    sT[mt][nt] = z;
                }
            }

            // causal mask (only the last two k-tiles can touch the diagonal)
            if (kt >= nk - 2) {
#pragma unroll
                for (int mt = 0; mt < 4; mt++)
#pragma unroll
                    for (int nt = 0; nt < 2; nt++)
#pragma unroll
                        for (int r = 0; r < 4; r++) {
                            const int key  = kt * 64 + mt * 16 + quad * 4 + r;
                            const int qrow = q0 + nt * 16 + l16;
                            if (key > qrow) sT[mt][nt][r] = -1e30f;
                        }
            }

            // online softmax: per lane only 2 query-rows of state
            float alpha[2];
#pragma unroll
            for (int nt = 0; nt < 2; nt++) {
                float mx = -1e30f;
#pragma unroll
                for (int mt = 0; mt < 4; mt++) {
                    float a01 = fmaxf(sT[mt][nt][0], sT[mt][nt][1]);
                    float a23 = fmaxf(sT[mt][nt][2], sT[mt][nt][3]);
                    mx = fmaxf(mx, fmaxf(a01, a23));
                }
                mx = fmaxf(mx, __shfl_xor(mx, 16, 64));
                mx = fmaxf(mx, __shfl_xor(mx, 32, 64));
                const float mn = fmaxf(m_old[nt], mx);
                alpha[nt] = __expf(m_old[nt] - mn);
                m_old[nt] = mn;
                float rs = 0.f;
#pragma unroll
                for (int mt = 0; mt < 4; mt++)
#pragma unroll
                    for (int r = 0; r < 4; r++) {
                        const float e = __expf(sT[mt][nt][r] - mn);
                        sT[mt][nt][r] = e;
                        rs += e;
                    }
                rs += __shfl_xor(rs, 16, 64);
                rs += __shfl_xor(rs, 32, 64);
                l_sum[nt] = l_sum[nt] * alpha[nt] + rs;
            }

            // P^T -> per-wave LDS (packed b64), rescale O accumulator
#pragma unroll
            for (int mt = 0; mt < 4; mt++)
#pragma unroll
                for (int nt = 0; nt < 2; nt++) {
                    uint2 pk;
                    pk.x = pk_bf16(sT[mt][nt][0], sT[mt][nt][1]);
                    pk.y = pk_bf16(sT[mt][nt][2], sT[mt][nt][3]);
                    *(uint2*)&PlT[wave][nt * 16 + l16][mt * 16 + quad * 4] = pk;
                    acc[mt][nt] *= alpha[nt];
                }
            // no barrier: PlT[wave] is wave-private; in-wave DS ordering suffices

            // O^T += V^T · P^T
#pragma unroll
            for (int ks = 0; ks < 2; ks++) {
                bf16x8 bp[2];
#pragma unroll
                for (int nt = 0; nt < 2; nt++)
                    bp[nt] = *(const bf16x8*)&PlT[wave][nt * 16 + l16][ks * 32 + quad * 8];
#pragma unroll
                for (int mt = 0; mt < 4; mt++) {
                    const int vr = mt * 16 + l16;
                    bf16x8 av = *(const bf16x8*)&Vt[vr][((ks * 4 + quad) ^ (vr & 7)) * 8];
#pragma unroll
                    for (int nt = 0; nt < 2; nt++)
                        acc[mt][nt] = __builtin_amdgcn_mfma_f32_16x16x32_bf16(av, bp[nt], acc[mt][nt], 0, 0, 0);
                }
            }
        }

        // epilogue: O^T C-layout -> Cx[b][qrow][h*64+d], packed b64 stores
#pragma unroll
        for (int nt = 0; nt < 2; nt++) {
            const float inv = __builtin_amdgcn_rcpf(l_sum[nt]);
            const int qrow = q0 + nt * 16 + l16;
#pragma unroll
            for (int mt = 0; mt < 4; mt++) {
                uint2 pk;
                pk.x = pk_bf16(acc[mt][nt][0] * inv, acc[mt][nt][1] * inv);
                pk.y = pk_bf16(acc[mt][nt][2] * inv, acc[mt][nt][3] * inv);
                *(uint2*)(Cx + ((size_t)(bl * Sq + qrow)) * Dm + h * HDim + mt * 16 + quad * 4) = pk;
            }
        }
    }
}

// ---------------------------------------------------------------------------
// Kernel 3: output projection.  Cx bf16 @ WoT + bo -> fp32 out.
// ---------------------------------------------------------------------------
__global__ __launch_bounds__(256, 2)
void out_gemm(const bf16* __restrict__ Cx, const bf16* __restrict__ WtO,
              const float* __restrict__ bo, float* __restrict__ out, int mbase)
{
    __shared__ __align__(16) bf16 As2[128][64];
    __shared__ __align__(16) bf16 Bs2[128][64];

    const int tid  = threadIdx.x;
    const int wave = tid >> 6, lane = tid & 63, quad = lane >> 4, l16 = lane & 15;
    const int bm = blockIdx.y * 128, bn = blockIdx.x * 128;
    const int wm = (wave >> 1) * 64, wn = (wave & 1) * 64;

    floatx4 acc[4][4];
#pragma unroll
    for (int i = 0; i < 4; i++)
#pragma unroll
        for (int j = 0; j < 4; j++) acc[i][j] = (floatx4){0.f, 0.f, 0.f, 0.f};

    for (int k0 = 0; k0 < 1024; k0 += 64) {
        __syncthreads();
#pragma unroll
        for (int i = 0; i < 4; i++) {
            const int row = wave * 32 + i * 8 + (lane >> 3);
            const int lb  = (lane & 7) ^ (row & 7);
            const bf16* ga = Cx  + (size_t)(bm + row) * 1024 + k0 + lb * 8;
            const bf16* gb = WtO + (size_t)(bn + row) * 1024 + k0 + lb * 8;
            dma16((const void*)ga, (void*)&As2[wave * 32 + i * 8][0]);
            dma16((const void*)gb, (void*)&Bs2[wave * 32 + i * 8][0]);
        }
        __syncthreads();

#pragma unroll
        for (int kk = 0; kk < 2; kk++) {
            bf16x8 a[4], b[4];
#pragma unroll
            for (int tm = 0; tm < 4; tm++) {
                const int m = wm + tm * 16 + l16;
                const int phys = (kk * 4 + quad) ^ (m & 7);
                a[tm] = *(const bf16x8*)&As2[m][phys * 8];
            }
#pragma unroll
            for (int tn = 0; tn < 4; tn++) {
                const int n = wn + tn * 16 + l16;
                const int phys = (kk * 4 + quad) ^ (n & 7);
                b[tn] = *(const bf16x8*)&Bs2[n][phys * 8];
            }
#pragma unroll
            for (int tm = 0; tm < 4; tm++)
#pragma unroll
                for (int tn = 0; tn < 4; tn++)
                    acc[tm][tn] = __builtin_amdgcn_mfma_f32_16x16x32_bf16(a[tm], b[tn], acc[tm][tn], 0, 0, 0);
        }
    }

#pragma unroll
    for (int tm = 0; tm < 4; tm++)
#pragma unroll
        for (int tn = 0; tn < 4; tn++)
#pragma unroll
            for (int r = 0; r < 4; r++) {
                const int m = bm + wm + tm * 16 + quad * 4 + r;
                const int n = bn + wn + tn * 16 + l16;
                out[(size_t)(mbase + m) * 1024 + n] = acc[tm][tn][r] + bo[n];
            }
}

// ---------------------------------------------------------------------------
extern "C" void kernel_launch(void* const* d_in, const int* in_sizes, int n_in,
                              void* d_out, int out_size, void* d_ws, size_t ws_size,
                              hipStream_t stream)
{
    const float* x  = (const float*)d_in[0];
    const float* Wq = (const float*)d_in[1];
    const float* Wk = (const float*)d_in[2];
    const float* Wv = (const float*)d_in[3];
    const float* Wo = (const float*)d_in[4];
    const float* bo = (const float*)d_in[5];
    float* out = (float*)d_out;

    const size_t M1 = 1024 * 1024;
    const size_t XE = (size_t)8192 * 1024;

    if (ws_size >= (size_t)72 * 1024 * 1024) {
        // primary: Wt 8MB | xb 16 (aliased by Cx) | Qb 16 | Kb 16 | VT 16
        bf16* Wt = (bf16*)d_ws;
        bf16* xb = Wt + 4 * M1;
        bf16* Qb = xb + XE;
        bf16* Kb = Qb + XE;
        bf16* VT = Kb + XE;
        bf16* Cx = xb;  // alias: xb dead after qkv_gemm

        conv_x<<<dim3(4096), 256, 0, stream>>>(x, xb);
        prep_weights<<<dim3(16, 16, 4), 256, 0, stream>>>(Wq, Wk, Wv, Wo, Wt);
        qkv_gemm<1><<<dim3(8, 64, 3), 256, 0, stream>>>(x, xb, Wt, Qb, Kb, VT);
        attn<<<dim3(8, 64), 256, 0, stream>>>(Qb, Kb, VT, Cx);
        out_gemm<<<dim3(8, 64), 256, 0, stream>>>(Cx, Wt + 3 * M1, bo, out, 0);
    } else {
        // fallback (64 MB): Wt 8 | Qb 16 | Kb 16 | VT 16 | Cx 8
        bf16* Wt = (bf16*)d_ws;
        bf16* Qb = Wt + 4 * M1;
        bf16* Kb = Qb + XE;
        bf16* VT = Kb + XE;
        bf16* Cx = VT + XE;

        prep_weights<<<dim3(16, 16, 4), 256, 0, stream>>>(Wq, Wk, Wv, Wo, Wt);
        qkv_gemm<0><<<dim3(8, 64, 3), 256, 0, stream>>>(x, nullptr, Wt, Qb, Kb, VT);
        const size_t chunk = (size_t)2 * Hh * Sq * HDim;
        for (int c = 0; c < 2; c++) {
            attn<<<dim3(8, 32), 256, 0, stream>>>(Qb + c * chunk, Kb + c * chunk,
                                                  VT + c * chunk, Cx);
            out_gemm<<<dim3(8, 32), 256, 0, stream>>>(Cx, Wt + 3 * M1, bo, out, c * 4096);
        }
    }
}